// Round 2
// baseline (384.791 us; speedup 1.0000x reference)
//
#include <hip/hip_runtime.h>
#include <hip/hip_bf16.h>

// Problem constants (static per setup_inputs()):
//   N = 204800 atoms, F = 128 features, G = 4096 graphs, M = 128 max atoms.
// Output layout in d_out (float32): result[G*M*F] then mask[G*M] (1.0 / 0.0).

constexpr int kF  = 128;           // features per atom
constexpr int kM  = 128;           // max atoms per graph
constexpr int kG  = 4096;          // num graphs
constexpr int kF4 = kF / 4;        // float4 per row = 32

// ---------------------------------------------------------------------------
// Kernel 1: per-graph start/count via binary search on sorted batch_ids.
// One thread per graph; ~18 cached loads per lower_bound. Negligible cost.
// ---------------------------------------------------------------------------
__global__ void bounds_kernel(const int* __restrict__ bids, int N, int G,
                              int* __restrict__ starts, int* __restrict__ counts) {
    int g = blockIdx.x * blockDim.x + threadIdx.x;
    if (g >= G) return;
    auto lb = [&](int v) {
        int lo = 0, hi = N;
        while (lo < hi) {
            int mid = (lo + hi) >> 1;
            if (bids[mid] < v) lo = mid + 1; else hi = mid;
        }
        return lo;
    };
    int s = lb(g);
    int e = lb(g + 1);
    starts[g] = s;
    counts[g] = e - s;
}

// ---------------------------------------------------------------------------
// Kernel 2: fill result. One float4 per thread-iteration over [G*M][kF4].
// Row (g,p): copy x[starts[g]+p] if p < counts[g], else zeros.
// Reads + writes are unit-stride float4 -> fully coalesced (G2/G13).
// d_out is poisoned 0xAA before every launch, so padding MUST be written.
// ---------------------------------------------------------------------------
__global__ void fill_kernel(const float4* __restrict__ x4,
                            const int* __restrict__ starts,
                            const int* __restrict__ counts,
                            float4* __restrict__ out4) {
    const long long total = (long long)kG * kM * kF4;  // 16,777,216 float4
    long long stride = (long long)gridDim.x * blockDim.x;
    for (long long i = (long long)blockIdx.x * blockDim.x + threadIdx.x;
         i < total; i += stride) {
        int lane = (int)(i & (kF4 - 1));       // float4 index within row
        long long row = i >> 5;                // g*M + p
        int p = (int)(row & (kM - 1));
        int g = (int)(row >> 7);
        float4 v = make_float4(0.f, 0.f, 0.f, 0.f);
        if (p < counts[g]) {
            v = x4[(long long)(starts[g] + p) * kF4 + lane];
        }
        out4[i] = v;
    }
}

// ---------------------------------------------------------------------------
// Kernel 3: mask as float 1.0/0.0, float4-vectorized ([G][M/4]).
// ---------------------------------------------------------------------------
__global__ void mask_kernel(const int* __restrict__ counts,
                            float4* __restrict__ mask4) {
    int i = blockIdx.x * blockDim.x + threadIdx.x;   // 0 .. G*M/4-1
    constexpr int per_g = kM / 4;                    // 32 float4 per graph
    if (i >= kG * per_g) return;
    int g  = i >> 5;                 // i / 32
    int p0 = (i & 31) << 2;          // (i % 32) * 4
    int c  = counts[g];
    float4 v;
    v.x = (p0 + 0 < c) ? 1.f : 0.f;
    v.y = (p0 + 1 < c) ? 1.f : 0.f;
    v.z = (p0 + 2 < c) ? 1.f : 0.f;
    v.w = (p0 + 3 < c) ? 1.f : 0.f;
    mask4[i] = v;
}

extern "C" void kernel_launch(void* const* d_in, const int* in_sizes, int n_in,
                              void* d_out, int out_size, void* d_ws, size_t ws_size,
                              hipStream_t stream) {
    const float* x    = (const float*)d_in[0];
    const int*   bids = (const int*)d_in[1];   // harness delivers integer inputs as int32
    const int    N    = in_sizes[0] / kF;      // 204800

    float* out = (float*)d_out;
    // workspace layout: starts[kG], counts[kG]
    int* starts = (int*)d_ws;
    int* counts = starts + kG;

    // 1) per-graph bounds
    bounds_kernel<<<(kG + 255) / 256, 256, 0, stream>>>(bids, N, kG, starts, counts);

    // 2) padded scatter (grid-stride; ~2048-4096 blocks per G11)
    fill_kernel<<<4096, 256, 0, stream>>>((const float4*)x, starts, counts,
                                          (float4*)out);

    // 3) mask
    float4* mask4 = (float4*)(out + (long long)kG * kM * kF);
    mask_kernel<<<(kG * (kM / 4) + 255) / 256, 256, 0, stream>>>(counts, mask4);
}

// Round 3
// 363.889 us; speedup vs baseline: 1.0574x; 1.0574x over previous
//
#include <hip/hip_runtime.h>
#include <hip/hip_bf16.h>

// Problem constants (static per setup_inputs()):
//   N = 204800 atoms, F = 128 features, G = 4096 graphs, M = 128 max atoms.
// Output layout in d_out (float32): result[G*M*F] then mask[G*M] (1.0 / 0.0).

constexpr int kF  = 128;           // features per atom
constexpr int kM  = 128;           // max atoms per graph
constexpr int kG  = 4096;          // num graphs
constexpr int kF4 = kF / 4;        // float4 per row = 32

constexpr int kThreads    = 256;
constexpr int kFillBlocks = 4096;
constexpr int kIters      = (kG * kM * kF4) / (kThreads * kFillBlocks); // = 16

// ---------------------------------------------------------------------------
// Kernel 1: starts[] via boundary diff on the SORTED batch_ids.
// Thread i writes starts[g] = i for every g in (bids[i-1], bids[i]].
// Streaming coalesced read (~800 KB), no dependent-load chains (vs the
// round-2 binary search: 36 serial cold loads/thread = latency-bound).
// starts has G+1 entries; counts[g] == starts[g+1] - starts[g].
// ---------------------------------------------------------------------------
__global__ void starts_kernel(const int* __restrict__ bids, int N,
                              int* __restrict__ starts) {
    int i = blockIdx.x * blockDim.x + threadIdx.x;
    if (i >= N) return;
    int b    = bids[i];
    int prev = (i == 0) ? -1 : bids[i - 1];
    for (int g = prev + 1; g <= b; ++g) starts[g] = i;   // usually 0 or 1 iter
    if (i == N - 1) {
        for (int g = b + 1; g <= kG; ++g) starts[g] = N; // tail incl. starts[kG]
    }
}

// ---------------------------------------------------------------------------
// Kernel 2: fill result. Fixed trip count + compile-time stride so the
// compiler fully unrolls -> 16 independent load chains per thread (MLP).
// Row (g,p): copy x[starts[g]+p] if p < count, else zeros. All accesses are
// unit-stride float4; d_out is poisoned 0xAA so padding MUST be written.
// ---------------------------------------------------------------------------
__global__ __launch_bounds__(kThreads)
void fill_kernel(const float4* __restrict__ x4,
                 const int* __restrict__ starts,
                 float4* __restrict__ out4) {
    const int base = blockIdx.x * kThreads + threadIdx.x;
#pragma unroll
    for (int it = 0; it < kIters; ++it) {
        const int i    = base + it * (kThreads * kFillBlocks); // < 2^24, int-safe
        const int lane = i & (kF4 - 1);        // float4 index within row
        const int row  = i >> 5;               // g*kM + p
        const int p    = row & (kM - 1);
        const int g    = row >> 7;
        const int s0   = starts[g];
        const int s1   = starts[g + 1];        // adjacent, cached (16 KB table)
        float4 v = make_float4(0.f, 0.f, 0.f, 0.f);
        if (p < s1 - s0) {
            v = x4[(s0 + p) * kF4 + lane];     // max idx 6.55M, int-safe
        }
        out4[i] = v;
    }
}

// ---------------------------------------------------------------------------
// Kernel 3: mask as float 1.0/0.0, float4-vectorized ([G][M/4]).
// ---------------------------------------------------------------------------
__global__ void mask_kernel(const int* __restrict__ starts,
                            float4* __restrict__ mask4) {
    int i = blockIdx.x * blockDim.x + threadIdx.x;   // 0 .. G*M/4-1
    if (i >= kG * (kM / 4)) return;
    int g  = i >> 5;                 // i / 32
    int p0 = (i & 31) << 2;          // (i % 32) * 4
    int c  = starts[g + 1] - starts[g];
    float4 v;
    v.x = (p0 + 0 < c) ? 1.f : 0.f;
    v.y = (p0 + 1 < c) ? 1.f : 0.f;
    v.z = (p0 + 2 < c) ? 1.f : 0.f;
    v.w = (p0 + 3 < c) ? 1.f : 0.f;
    mask4[i] = v;
}

extern "C" void kernel_launch(void* const* d_in, const int* in_sizes, int n_in,
                              void* d_out, int out_size, void* d_ws, size_t ws_size,
                              hipStream_t stream) {
    const float* x    = (const float*)d_in[0];
    const int*   bids = (const int*)d_in[1];   // harness delivers integer inputs as int32
    const int    N    = in_sizes[0] / kF;      // 204800

    float* out = (float*)d_out;
    int* starts = (int*)d_ws;                  // starts[kG+1]

    // 1) per-graph starts via boundary diff (streaming, ~3 us)
    starts_kernel<<<(N + kThreads - 1) / kThreads, kThreads, 0, stream>>>(bids, N, starts);

    // 2) padded scatter: exactly kIters iterations/thread, fully unrolled
    fill_kernel<<<kFillBlocks, kThreads, 0, stream>>>((const float4*)x, starts,
                                                      (float4*)out);

    // 3) mask
    float4* mask4 = (float4*)(out + (long long)kG * kM * kF);
    mask_kernel<<<(kG * (kM / 4) + kThreads - 1) / kThreads, kThreads, 0, stream>>>(starts, mask4);
}

// Round 6
// 357.596 us; speedup vs baseline: 1.0761x; 1.0176x over previous
//
#include <hip/hip_runtime.h>
#include <hip/hip_bf16.h>

// Problem constants (static per setup_inputs()):
//   N = 204800 atoms, F = 128 features, G = 4096 graphs, M = 128 max atoms.
// Output layout in d_out (float32): result[G*M*F] then mask[G*M] (1.0 / 0.0),
// contiguous. d_out/d_ws are poisoned 0xAA before every timed launch, so all
// padding and mask values must be written every call.

constexpr int kF  = 128;           // features per atom
constexpr int kM  = 128;           // max atoms per graph
constexpr int kG  = 4096;          // num graphs
constexpr int kF4 = kF / 4;        // float4 per row = 32

constexpr int kThreads    = 256;
constexpr int kFillBlocks = 4096;
constexpr int kResF4      = kG * kM * kF4;            // 16,777,216 float4
constexpr int kMaskF4     = kG * kM / 4;              // 131,072 float4
constexpr int kIters      = kResF4 / (kThreads * kFillBlocks); // = 16

// Native clang vector type: __builtin_nontemporal_* accepts vectors of float,
// unlike HIP's float4 (a HIP_vector_type class). Same 16B codegen (dwordx4).
typedef float fx4 __attribute__((ext_vector_type(4)));

// ---------------------------------------------------------------------------
// Kernel 1: starts[] via boundary diff on the SORTED batch_ids.
// Thread i writes starts[g] = i for every g in (bids[i-1], bids[i]].
// One streaming coalesced read (~800 KB), ~3-5 us.
// starts has G+1 entries; counts[g] == starts[g+1] - starts[g].
// ---------------------------------------------------------------------------
__global__ void starts_kernel(const int* __restrict__ bids, int N,
                              int* __restrict__ starts) {
    int i = blockIdx.x * blockDim.x + threadIdx.x;
    if (i >= N) return;
    int b    = bids[i];
    int prev = (i == 0) ? -1 : bids[i - 1];
    for (int g = prev + 1; g <= b; ++g) starts[g] = i;   // usually 0 or 1 iter
    if (i == N - 1) {
        for (int g = b + 1; g <= kG; ++g) starts[g] = N; // tail incl. starts[kG]
    }
}

// ---------------------------------------------------------------------------
// Kernel 2 (fused fill + mask).
// Result: one fx4 per thread-iteration over [G*M][kF4]; row (g,p) copies
// x[starts[g]+p] when p < count, else zeros. Fixed trip count + compile-time
// stride -> fully unrolled, 16 independent load chains per thread.
// Streams are read-once / write-once -> nontemporal (nt) hints to avoid
// L2 allocation thrash (358 MB traffic vs 32 MB aggregate L2).
// Mask: first kMaskF4 threads write one fx4 of 1.0/0.0 right after result.
// ---------------------------------------------------------------------------
__global__ __launch_bounds__(kThreads)
void fill_kernel(const fx4* __restrict__ x4,
                 const int* __restrict__ starts,
                 fx4* __restrict__ out4,
                 fx4* __restrict__ mask4) {
    const int base = blockIdx.x * kThreads + threadIdx.x;
#pragma unroll
    for (int it = 0; it < kIters; ++it) {
        const int i    = base + it * (kThreads * kFillBlocks); // < 2^24, int-safe
        const int lane = i & (kF4 - 1);        // fx4 index within row
        const int row  = i >> 5;               // g*kM + p
        const int p    = row & (kM - 1);
        const int g    = row >> 7;
        const int s0   = starts[g];
        const int s1   = starts[g + 1];        // adjacent, cached (16 KB table)
        fx4 v = (fx4)(0.f);
        if (p < s1 - s0) {
            v = __builtin_nontemporal_load(&x4[(s0 + p) * kF4 + lane]);
        }
        __builtin_nontemporal_store(v, &out4[i]);
    }
    // Fused mask tail: threads 0 .. kMaskF4-1 (blocks 0..511) each write one
    // fx4 of the [G][M] mask (4 atom slots).
    if (base < kMaskF4) {
        const int g  = base >> 5;              // base / 32
        const int p0 = (base & 31) << 2;       // (base % 32) * 4
        const int c  = starts[g + 1] - starts[g];
        fx4 v;
        v.x = (p0 + 0 < c) ? 1.f : 0.f;
        v.y = (p0 + 1 < c) ? 1.f : 0.f;
        v.z = (p0 + 2 < c) ? 1.f : 0.f;
        v.w = (p0 + 3 < c) ? 1.f : 0.f;
        __builtin_nontemporal_store(v, &mask4[base]);
    }
}

extern "C" void kernel_launch(void* const* d_in, const int* in_sizes, int n_in,
                              void* d_out, int out_size, void* d_ws, size_t ws_size,
                              hipStream_t stream) {
    const float* x    = (const float*)d_in[0];
    const int*   bids = (const int*)d_in[1];   // harness delivers integer inputs as int32
    const int    N    = in_sizes[0] / kF;      // 204800

    float* out = (float*)d_out;
    int* starts = (int*)d_ws;                  // starts[kG+1]

    // 1) per-graph starts via boundary diff (streaming)
    starts_kernel<<<(N + kThreads - 1) / kThreads, kThreads, 0, stream>>>(bids, N, starts);

    // 2) fused padded scatter + mask
    fx4* mask4 = (fx4*)(out + (long long)kG * kM * kF);
    fill_kernel<<<kFillBlocks, kThreads, 0, stream>>>((const fx4*)x, starts,
                                                      (fx4*)out, mask4);
}

// Round 7
// 342.482 us; speedup vs baseline: 1.1235x; 1.0441x over previous
//
#include <hip/hip_runtime.h>
#include <hip/hip_bf16.h>

// Problem constants (static per setup_inputs()):
//   N = 204800 atoms, F = 128 features, G = 4096 graphs, M = 128 max atoms.
// Output layout in d_out (float32): result[G*M*F] then mask[G*M] (1.0/0.0),
// contiguous. d_out/d_ws are poisoned 0xAA before every timed launch, so all
// padding and mask values must be written every call.
//
// Single fused kernel: block = graph. Per-block bounds via wave-parallel
// 64-way lower_bound on the sorted batch_ids (3 ballot rounds), then stream
// the 64 KB slab + 512 B mask row with nontemporal dwordx4.

constexpr int kF  = 128;           // features per atom
constexpr int kM  = 128;           // max atoms per graph
constexpr int kG  = 4096;          // num graphs
constexpr int kF4 = kF / 4;        // fx4 per row = 32
constexpr int kSlabF4 = kM * kF4;  // 4096 fx4 per graph slab

typedef float fx4 __attribute__((ext_vector_type(4)));

// ---------------------------------------------------------------------------
// Wave-parallel lower_bound: first idx in [0,N] with bids[idx] >= T.
// Invariant: pred(lo)=false (lo=-1 sentinel), pred(hi)=true (hi=N sentinel).
// Each round 64 lanes probe the interior -> narrow ~64x; 3 rounds for N=205k.
// lo/hi stay wave-uniform (derived from ballot), so the loop is uniform.
// ---------------------------------------------------------------------------
__device__ __forceinline__ int wave_lower_bound(const int* __restrict__ bids,
                                                int N, int T, int lane) {
    int lo = -1, hi = N;
    while (hi - lo > 1) {
        const long long count = hi - lo - 1;                 // interior size >= 1
        const int pos = lo + 1 + (int)(((long long)lane * count) >> 6);
        const bool pred = (bids[pos] >= T);
        const unsigned long long bal = __ballot(pred);
        if (bal == 0) {
            lo = lo + 1 + (int)((63LL * count) >> 6);        // pos of lane 63
        } else {
            const int j = __ffsll(bal) - 1;                  // first pred-true lane
            hi = lo + 1 + (int)(((long long)j * count) >> 6);
            if (j > 0)
                lo = lo + 1 + (int)(((long long)(j - 1) * count) >> 6);
        }
    }
    return hi;
}

__global__ __launch_bounds__(256)
void fused_kernel(const fx4* __restrict__ x4, const int* __restrict__ bids,
                  int N, fx4* __restrict__ out4, fx4* __restrict__ mask4) {
    const int g   = blockIdx.x;            // one graph per block
    const int tid = threadIdx.x;
    __shared__ int sh[2];                  // {starts[g], starts[g+1]}

    if (tid < 128) {                       // waves 0,1: bounds for g and g+1
        const int which = tid >> 6;
        const int lane  = tid & 63;
        const int r = wave_lower_bound(bids, N, g + which, lane);
        if (lane == 0) sh[which] = r;
    }
    __syncthreads();
    const int s0 = sh[0];
    const int c  = sh[1] - s0;             // atoms in this graph (<= kM)

    // Result slab: 4096 fx4 = 128 rows x 32; 16 fx4 per thread, coalesced.
    fx4* slab = out4 + ((long long)g << 12);
#pragma unroll
    for (int it = 0; it < kSlabF4 / 256; ++it) {
        const int idx  = it * 256 + tid;
        const int row  = idx >> 5;         // within-graph atom position
        const int lane = idx & (kF4 - 1);
        fx4 v = (fx4)(0.f);
        if (row < c) {
            v = __builtin_nontemporal_load(&x4[(s0 + row) * kF4 + lane]);
        }
        __builtin_nontemporal_store(v, &slab[idx]);
    }

    // Mask row: 128 floats = 32 fx4, threads 0..31.
    if (tid < 32) {
        const int p0 = tid << 2;
        fx4 v;
        v.x = (p0 + 0 < c) ? 1.f : 0.f;
        v.y = (p0 + 1 < c) ? 1.f : 0.f;
        v.z = (p0 + 2 < c) ? 1.f : 0.f;
        v.w = (p0 + 3 < c) ? 1.f : 0.f;
        __builtin_nontemporal_store(v, &mask4[(g << 5) + tid]);
    }
}

extern "C" void kernel_launch(void* const* d_in, const int* in_sizes, int n_in,
                              void* d_out, int out_size, void* d_ws, size_t ws_size,
                              hipStream_t stream) {
    const float* x    = (const float*)d_in[0];
    const int*   bids = (const int*)d_in[1];   // integer inputs arrive as int32
    const int    N    = in_sizes[0] / kF;      // 204800

    float* out  = (float*)d_out;
    fx4* mask4  = (fx4*)(out + (long long)kG * kM * kF);

    fused_kernel<<<kG, 256, 0, stream>>>((const fx4*)x, bids, N,
                                         (fx4*)out, mask4);
}